// Round 3
// baseline (461.228 us; speedup 1.0000x reference)
//
#include <hip/hip_runtime.h>

typedef unsigned short u16;
typedef __attribute__((ext_vector_type(8))) short bfrag;   // 8 bf16 = 4 VGPRs
typedef __attribute__((ext_vector_type(4))) float f32x4;

#define MFMA16(a, b, c) __builtin_amdgcn_mfma_f32_16x16x32_bf16((a), (b), (c), 0, 0, 0)

__device__ __forceinline__ u16 f2bf(float f) {
  unsigned u = __builtin_bit_cast(unsigned, f);
  u += 0x7fffu + ((u >> 16) & 1u);   // RNE
  return (u16)(u >> 16);
}

// ---------------- K0: f32 -> bf16 cast ----------------
__global__ __launch_bounds__(256)
void k_cast(const float* __restrict__ in, u16* __restrict__ out, int n4) {
  int i = blockIdx.x * blockDim.x + threadIdx.x;
  if (i >= n4) return;
  float4 v = reinterpret_cast<const float4*>(in)[i];
  uint2 o;
  o.x = (unsigned)f2bf(v.x) | ((unsigned)f2bf(v.y) << 16);
  o.y = (unsigned)f2bf(v.z) | ((unsigned)f2bf(v.w) << 16);
  reinterpret_cast<uint2*>(out)[i] = o;
}

// ---------------- K1: h = softmax_hd(x @ W_in^T + b_in), v = sum_s h ----------------
// C[gr][gc] = sum_k xb[gr][k]*wb[gc][k]. Tiles: 128 rows x 64 cols, 4 waves (32 rows each).
// Wave col-span = 64 = one head group -> in-wave softmax.
__global__ __launch_bounds__(256)
void k_gemm1(const u16* __restrict__ xb, const u16* __restrict__ wb,
             const float* __restrict__ bias, u16* __restrict__ h_s,
             float* __restrict__ v) {
  int bx = blockIdx.x & 15;        // 16 col tiles of 64
  int by = blockIdx.x >> 4;        // 32 row tiles of 128
  int tid = threadIdx.x;
  int w = tid >> 6, lane = tid & 63, lr = lane & 15, hi = lane >> 4;
  int row0 = by * 128 + w * 32;
  int col0 = bx * 64;

  f32x4 acc[2][4] = {};
  const u16* Ab = xb + (size_t)row0 * 1024;
  const u16* Bb = wb + (size_t)col0 * 1024;

  for (int k0 = 0; k0 < 1024; k0 += 32) {
    int ko = k0 + hi * 8;
    bfrag a[2], b[4];
#pragma unroll
    for (int mi = 0; mi < 2; mi++)
      a[mi] = *reinterpret_cast<const bfrag*>(Ab + (mi * 16 + lr) * 1024 + ko);
#pragma unroll
    for (int ni = 0; ni < 4; ni++)
      b[ni] = *reinterpret_cast<const bfrag*>(Bb + (ni * 16 + lr) * 1024 + ko);
#pragma unroll
    for (int mi = 0; mi < 2; mi++)
#pragma unroll
      for (int ni = 0; ni < 4; ni++)
        acc[mi][ni] = MFMA16(a[mi], b[ni], acc[mi][ni]);
  }

  float bia[4];
#pragma unroll
  for (int ni = 0; ni < 4; ni++) bia[ni] = bias[col0 + ni * 16 + lr];

  int b_idx = row0 >> 9;      // batch (tile never crosses a 512-row boundary)
  int n_idx = bx;             // head  (col0/64)
  float vpart[4] = {0.f, 0.f, 0.f, 0.f};
#pragma unroll
  for (int mi = 0; mi < 2; mi++) {
#pragma unroll
    for (int i = 0; i < 4; i++) {
      float x0 = acc[mi][0][i] + bia[0];
      float x1 = acc[mi][1][i] + bia[1];
      float x2 = acc[mi][2][i] + bia[2];
      float x3 = acc[mi][3][i] + bia[3];
      float mx = fmaxf(fmaxf(x0, x1), fmaxf(x2, x3));
      mx = fmaxf(mx, __shfl_xor(mx, 1));
      mx = fmaxf(mx, __shfl_xor(mx, 2));
      mx = fmaxf(mx, __shfl_xor(mx, 4));
      mx = fmaxf(mx, __shfl_xor(mx, 8));
      float e0 = __expf(x0 - mx), e1 = __expf(x1 - mx),
            e2 = __expf(x2 - mx), e3 = __expf(x3 - mx);
      float sm = e0 + e1 + e2 + e3;
      sm += __shfl_xor(sm, 1); sm += __shfl_xor(sm, 2);
      sm += __shfl_xor(sm, 4); sm += __shfl_xor(sm, 8);
      float inv = 1.0f / sm;
      e0 *= inv; e1 *= inv; e2 *= inv; e3 *= inv;
      int s = (row0 + mi * 16 + hi * 4 + i) & 511;
      size_t hb = ((size_t)(b_idx * 16 + n_idx) * 512 + s) * 64;
      h_s[hb + 0  + lr] = f2bf(e0);
      h_s[hb + 16 + lr] = f2bf(e1);
      h_s[hb + 32 + lr] = f2bf(e2);
      h_s[hb + 48 + lr] = f2bf(e3);
      vpart[0] += e0; vpart[1] += e1; vpart[2] += e2; vpart[3] += e3;
    }
  }
#pragma unroll
  for (int ni = 0; ni < 4; ni++) {
    float t = vpart[ni];
    t += __shfl_xor(t, 16);
    t += __shfl_xor(t, 32);
    if (hi == 0) atomicAdd(&v[(b_idx * 16 + n_idx) * 64 + ni * 16 + lr], t);
  }
}

// ---------------- K2: h_t[bn][e][s] = h_s[bn][s][e] (LDS transpose, XOR swizzle) ----------------
__global__ __launch_bounds__(256)
void k_transpose(const u16* __restrict__ h_s, u16* __restrict__ h_t) {
  int bn = blockIdx.x;
  const u16* src = h_s + (size_t)bn * 32768;
  u16* dst = h_t + (size_t)bn * 32768;
  __shared__ u16 lds[64 * 512];
  int t = threadIdx.x;
  for (int k = 0; k < 64; k++) {
    int p = t + 256 * k;
    int s = p >> 5, e0 = (p & 31) * 2;
    unsigned u = reinterpret_cast<const unsigned*>(src)[p];
    lds[e0 * 512 + (s ^ e0)] = (u16)(u & 0xffffu);
    lds[(e0 + 1) * 512 + (s ^ (e0 + 1))] = (u16)(u >> 16);
  }
  __syncthreads();
  int e = t >> 2, s0 = (t & 3) * 128;
  for (int sb = 0; sb < 128; sb += 8) {
    unsigned pk[4];
#pragma unroll
    for (int jj = 0; jj < 4; jj++) {
      u16 lo = lds[e * 512 + ((s0 + sb + jj * 2) ^ e)];
      u16 hc = lds[e * 512 + ((s0 + sb + jj * 2 + 1) ^ e)];
      pk[jj] = (unsigned)lo | ((unsigned)hc << 16);
    }
    uint4 ov; ov.x = pk[0]; ov.y = pk[1]; ov.z = pk[2]; ov.w = pk[3];
    *reinterpret_cast<uint4*>(dst + e * 512 + s0 + sb) = ov;
  }
}

// ---------------- K3: z[b,n,o,e] = sum_h attn_w[o,n,e,h] * v[b,n,h] ----------------
__global__ __launch_bounds__(256)
void k_z(const float* __restrict__ attn_w, const float* __restrict__ v,
         u16* __restrict__ z) {
  int n = blockIdx.x >> 3, ot = blockIdx.x & 7;
  __shared__ float vl[512];
  int t = threadIdx.x;
  vl[t]       = v[((t >> 6) * 16 + n) * 64 + (t & 63)];
  vl[t + 256] = v[(((t + 256) >> 6) * 16 + n) * 64 + (t & 63)];
  __syncthreads();
  for (int it = 0; it < 16; it++) {
    int pi = it * 256 + t;
    int ol = pi >> 6, e = pi & 63;
    int o = ot * 64 + ol;
    const float4* wp = reinterpret_cast<const float4*>(attn_w + ((size_t)(o * 16 + n) * 64 + e) * 64);
    float acc[8] = {};
#pragma unroll 4
    for (int j = 0; j < 16; j++) {
      float4 wv = wp[j];
#pragma unroll
      for (int bb = 0; bb < 8; bb++) {
        acc[bb] += wv.x * vl[bb * 64 + j * 4]
                 + wv.y * vl[bb * 64 + j * 4 + 1]
                 + wv.z * vl[bb * 64 + j * 4 + 2]
                 + wv.w * vl[bb * 64 + j * 4 + 3];
      }
    }
#pragma unroll
    for (int bb = 0; bb < 8; bb++)
      z[((size_t)(bb * 16 + n) * 512 + o) * 64 + e] = f2bf(acc[bb]);
  }
}

// ---------------- K4: scores -> softmax -> attn1 (f32 out) -> out_small ----------------
// Block: (b,n, 32-row s-tile). 8 waves. Pass1: each wave = 32 rows x 64-o strip (K=64).
// Softmax over 512 o via cross-wave LDS reduce. attn1 kept bf16 in swizzled LDS.
// Pass2: out_small(32x64) = attn1(32x512) @ h(512x64), wave = 16x16 tile, K=512.
__global__ __launch_bounds__(512)
void k_attn(const u16* __restrict__ h_s, const u16* __restrict__ h_t,
            const u16* __restrict__ z, float* __restrict__ attn1,
            u16* __restrict__ outs) {
  int bid = blockIdx.x;
  int bn = bid >> 4;
  int s0 = (bid & 15) * 32;
  int b = bn >> 4, n = bn & 15;
  int tid = threadIdx.x;
  int w = tid >> 6, lane = tid & 63, lr = lane & 15, hi = lane >> 4;

  __shared__ u16 pa[32 * 512];     // attn1 bf16, 8-elem-granule XOR swizzle
  __shared__ float red[8 * 32];
  __shared__ float gred[32];

  const u16* hsb = h_s + (size_t)bn * 32768;
  const u16* htb = h_t + (size_t)bn * 32768;
  const u16* zb  = z   + (size_t)bn * 32768;

  f32x4 acc[2][4] = {};
  {
    bfrag a[2][2], bb[4][2];
#pragma unroll
    for (int kk = 0; kk < 2; kk++) {
      int ko = kk * 32 + hi * 8;
#pragma unroll
      for (int mi = 0; mi < 2; mi++)
        a[mi][kk] = *reinterpret_cast<const bfrag*>(hsb + (s0 + mi * 16 + lr) * 64 + ko);
#pragma unroll
      for (int ni = 0; ni < 4; ni++)
        bb[ni][kk] = *reinterpret_cast<const bfrag*>(zb + (w * 64 + ni * 16 + lr) * 64 + ko);
    }
#pragma unroll
    for (int kk = 0; kk < 2; kk++)
#pragma unroll
      for (int mi = 0; mi < 2; mi++)
#pragma unroll
        for (int ni = 0; ni < 4; ni++)
          acc[mi][ni] = MFMA16(a[mi][kk], bb[ni][kk], acc[mi][ni]);
  }
  const float scale = 6.9053396600248786e-04f;  // 1/(64*sqrt(512))
#pragma unroll
  for (int mi = 0; mi < 2; mi++)
#pragma unroll
    for (int ni = 0; ni < 4; ni++)
#pragma unroll
      for (int i = 0; i < 4; i++) acc[mi][ni][i] *= scale;

  // per-row max (strip) -> LDS
#pragma unroll
  for (int mi = 0; mi < 2; mi++)
#pragma unroll
    for (int i = 0; i < 4; i++) {
      float mx = fmaxf(fmaxf(acc[mi][0][i], acc[mi][1][i]),
                       fmaxf(acc[mi][2][i], acc[mi][3][i]));
      mx = fmaxf(mx, __shfl_xor(mx, 1));
      mx = fmaxf(mx, __shfl_xor(mx, 2));
      mx = fmaxf(mx, __shfl_xor(mx, 4));
      mx = fmaxf(mx, __shfl_xor(mx, 8));
      if (lr == 0) red[w * 32 + mi * 16 + hi * 4 + i] = mx;
    }
  __syncthreads();
  if (tid < 32) {
    float g = red[tid];
#pragma unroll
    for (int w2 = 1; w2 < 8; w2++) g = fmaxf(g, red[w2 * 32 + tid]);
    gred[tid] = g;
  }
  __syncthreads();
  float p[2][4][4];
#pragma unroll
  for (int mi = 0; mi < 2; mi++)
#pragma unroll
    for (int i = 0; i < 4; i++) {
      float gm = gred[mi * 16 + hi * 4 + i];
      float sm = 0.f;
#pragma unroll
      for (int ni = 0; ni < 4; ni++) {
        p[mi][ni][i] = __expf(acc[mi][ni][i] - gm);
        sm += p[mi][ni][i];
      }
      sm += __shfl_xor(sm, 1); sm += __shfl_xor(sm, 2);
      sm += __shfl_xor(sm, 4); sm += __shfl_xor(sm, 8);
      if (lr == 0) red[w * 32 + mi * 16 + hi * 4 + i] = sm;
    }
  __syncthreads();
  if (tid < 32) {
    float g = 0.f;
#pragma unroll
    for (int w2 = 0; w2 < 8; w2++) g += red[w2 * 32 + tid];
    gred[tid] = 1.0f / g;
  }
  __syncthreads();
  float* a1b = attn1 + ((size_t)bn * 512 + s0) * 512;
#pragma unroll
  for (int mi = 0; mi < 2; mi++)
#pragma unroll
    for (int i = 0; i < 4; i++) {
      int r = mi * 16 + hi * 4 + i;
      float gi = gred[r];
#pragma unroll
      for (int ni = 0; ni < 4; ni++) {
        float val = p[mi][ni][i] * gi;
        int c = w * 64 + ni * 16 + lr;
        a1b[(size_t)r * 512 + c] = val;
        int g = c >> 3, j = c & 7;
        pa[r * 512 + ((g ^ (r & 7)) * 8 + j)] = f2bf(val);
      }
    }
  __syncthreads();
  // pass2: out_small = attn1 @ h  (B from h_t, contiguous k)
  int sm2 = (w >> 2) * 16, e0 = (w & 3) * 16;
  f32x4 oacc = {};
#pragma unroll 4
  for (int ks = 0; ks < 16; ks++) {
    int row = sm2 + lr;
    int g = ks * 4 + hi;
    bfrag av = *reinterpret_cast<const bfrag*>(pa + row * 512 + ((g ^ (row & 7)) * 8));
    bfrag bv = *reinterpret_cast<const bfrag*>(htb + (e0 + lr) * 512 + ks * 32 + hi * 8);
    oacc = MFMA16(av, bv, oacc);
  }
#pragma unroll
  for (int i = 0; i < 4; i++) {
    int s = s0 + sm2 + hi * 4 + i;
    outs[((size_t)b * 512 + s) * 1024 + n * 64 + e0 + lr] = f2bf(oacc[i]);
  }
}

// ---------------- K5: out = out_small @ W_out^T + b_out ----------------
__global__ __launch_bounds__(256)
void k_gemm2(const u16* __restrict__ ab, const u16* __restrict__ wb,
             const float* __restrict__ bias, float* __restrict__ out) {
  int bx = blockIdx.x & 15;
  int by = blockIdx.x >> 4;
  int tid = threadIdx.x;
  int w = tid >> 6, lane = tid & 63, lr = lane & 15, hi = lane >> 4;
  int row0 = by * 128 + w * 32;
  int col0 = bx * 64;
  f32x4 acc[2][4] = {};
  const u16* Ab = ab + (size_t)row0 * 1024;
  const u16* Bb = wb + (size_t)col0 * 1024;
  for (int k0 = 0; k0 < 1024; k0 += 32) {
    int ko = k0 + hi * 8;
    bfrag a[2], b[4];
#pragma unroll
    for (int mi = 0; mi < 2; mi++)
      a[mi] = *reinterpret_cast<const bfrag*>(Ab + (mi * 16 + lr) * 1024 + ko);
#pragma unroll
    for (int ni = 0; ni < 4; ni++)
      b[ni] = *reinterpret_cast<const bfrag*>(Bb + (ni * 16 + lr) * 1024 + ko);
#pragma unroll
    for (int mi = 0; mi < 2; mi++)
#pragma unroll
      for (int ni = 0; ni < 4; ni++)
        acc[mi][ni] = MFMA16(a[mi], b[ni], acc[mi][ni]);
  }
  float bia[4];
#pragma unroll
  for (int ni = 0; ni < 4; ni++) bia[ni] = bias[col0 + ni * 16 + lr];
#pragma unroll
  for (int mi = 0; mi < 2; mi++)
#pragma unroll
    for (int i = 0; i < 4; i++) {
      int r = row0 + mi * 16 + hi * 4 + i;
#pragma unroll
      for (int ni = 0; ni < 4; ni++)
        out[(size_t)r * 1024 + col0 + ni * 16 + lr] = acc[mi][ni][i] + bia[ni];
    }
}

extern "C" void kernel_launch(void* const* d_in, const int* in_sizes, int n_in,
                              void* d_out, int out_size, void* d_ws, size_t ws_size,
                              hipStream_t stream) {
  const float* x      = (const float*)d_in[0];
  const float* W_in   = (const float*)d_in[1];
  const float* b_in   = (const float*)d_in[2];
  const float* attn_w = (const float*)d_in[3];
  const float* W_out  = (const float*)d_in[4];
  const float* b_out  = (const float*)d_in[5];
  float* out   = (float*)d_out;                 // [8,512,1024] f32
  float* attn1 = out + 4194304;                 // [8,16,512,512] f32

  char* w = (char*)d_ws;
  u16*   xb    = (u16*)(w + 0);                 //  8 MB  [4096][1024]  (dead after k_gemm1)
  u16*   wbin  = (u16*)(w + 8388608);           //  2 MB  [1024][1024]
  u16*   wbout = (u16*)(w + 10485760);          //  2 MB
  u16*   h_s   = (u16*)(w + 12582912);          //  8 MB  [bn][512][64]
  u16*   h_t   = (u16*)(w + 20971520);          //  8 MB  [bn][64][512]
  u16*   zbuf  = (u16*)(w + 29360128);          //  8 MB  [bn][512][64]
  float* vbuf  = (float*)(w + 37748736);        // 32 KB  [bn][64]
  u16*   outs  = xb;                            //  reuses xb slot (k_attn writes after k_gemm1 done)
  // total ws footprint: 37,781,504 + 32,768 = 37,814,272 bytes

  hipMemsetAsync(vbuf, 0, 8192 * sizeof(float), stream);
  k_cast<<<4096, 256, 0, stream>>>(x, xb, 1048576);
  k_cast<<<1024, 256, 0, stream>>>(W_in, wbin, 262144);
  k_cast<<<1024, 256, 0, stream>>>(W_out, wbout, 262144);
  k_gemm1<<<512, 256, 0, stream>>>(xb, wbin, b_in, h_s, vbuf);
  k_transpose<<<128, 256, 0, stream>>>(h_s, h_t);
  k_z<<<128, 256, 0, stream>>>(attn_w, vbuf, zbuf);
  k_attn<<<2048, 512, 0, stream>>>(h_s, h_t, zbuf, attn1, outs);
  k_gemm2<<<512, 256, 0, stream>>>(outs, wbout, b_out, out);
}

// Round 4
// 434.131 us; speedup vs baseline: 1.0624x; 1.0624x over previous
//
#include <hip/hip_runtime.h>

typedef unsigned short u16;
typedef __attribute__((ext_vector_type(8))) short bfrag;   // 8 bf16 = 4 VGPRs
typedef __attribute__((ext_vector_type(4))) float f32x4;

#define MFMA16(a, b, c) __builtin_amdgcn_mfma_f32_16x16x32_bf16((a), (b), (c), 0, 0, 0)

__device__ __forceinline__ u16 f2bf(float f) {
  unsigned u = __builtin_bit_cast(unsigned, f);
  u += 0x7fffu + ((u >> 16) & 1u);   // RNE
  return (u16)(u >> 16);
}

// ---------------- K0: f32 -> bf16 cast ----------------
__global__ __launch_bounds__(256)
void k_cast(const float* __restrict__ in, u16* __restrict__ out, int n4) {
  int i = blockIdx.x * blockDim.x + threadIdx.x;
  if (i >= n4) return;
  float4 v = reinterpret_cast<const float4*>(in)[i];
  uint2 o;
  o.x = (unsigned)f2bf(v.x) | ((unsigned)f2bf(v.y) << 16);
  o.y = (unsigned)f2bf(v.z) | ((unsigned)f2bf(v.w) << 16);
  reinterpret_cast<uint2*>(out)[i] = o;
}

// ---------------- K1: h = softmax_hd(x @ W_in^T + b_in), v = sum_s h ----------------
// C[gr][gc] = sum_k xb[gr][k]*wb[gc][k]. Tiles: 128 rows x 64 cols, 4 waves (32 rows each).
// Wave col-span = 64 = one head group -> in-wave softmax.
__global__ __launch_bounds__(256)
void k_gemm1(const u16* __restrict__ xb, const u16* __restrict__ wb,
             const float* __restrict__ bias, u16* __restrict__ h_s,
             float* __restrict__ v) {
  int bx = blockIdx.x & 15;        // 16 col tiles of 64
  int by = blockIdx.x >> 4;        // 32 row tiles of 128
  int tid = threadIdx.x;
  int w = tid >> 6, lane = tid & 63, lr = lane & 15, hi = lane >> 4;
  int row0 = by * 128 + w * 32;
  int col0 = bx * 64;

  f32x4 acc[2][4] = {};
  const u16* Ab = xb + (size_t)row0 * 1024;
  const u16* Bb = wb + (size_t)col0 * 1024;

  for (int k0 = 0; k0 < 1024; k0 += 32) {
    int ko = k0 + hi * 8;
    bfrag a[2], b[4];
#pragma unroll
    for (int mi = 0; mi < 2; mi++)
      a[mi] = *reinterpret_cast<const bfrag*>(Ab + (mi * 16 + lr) * 1024 + ko);
#pragma unroll
    for (int ni = 0; ni < 4; ni++)
      b[ni] = *reinterpret_cast<const bfrag*>(Bb + (ni * 16 + lr) * 1024 + ko);
#pragma unroll
    for (int mi = 0; mi < 2; mi++)
#pragma unroll
      for (int ni = 0; ni < 4; ni++)
        acc[mi][ni] = MFMA16(a[mi], b[ni], acc[mi][ni]);
  }

  float bia[4];
#pragma unroll
  for (int ni = 0; ni < 4; ni++) bia[ni] = bias[col0 + ni * 16 + lr];

  int b_idx = row0 >> 9;      // batch (tile never crosses a 512-row boundary)
  int n_idx = bx;             // head  (col0/64)
  float vpart[4] = {0.f, 0.f, 0.f, 0.f};
#pragma unroll
  for (int mi = 0; mi < 2; mi++) {
#pragma unroll
    for (int i = 0; i < 4; i++) {
      float x0 = acc[mi][0][i] + bia[0];
      float x1 = acc[mi][1][i] + bia[1];
      float x2 = acc[mi][2][i] + bia[2];
      float x3 = acc[mi][3][i] + bia[3];
      float mx = fmaxf(fmaxf(x0, x1), fmaxf(x2, x3));
      mx = fmaxf(mx, __shfl_xor(mx, 1));
      mx = fmaxf(mx, __shfl_xor(mx, 2));
      mx = fmaxf(mx, __shfl_xor(mx, 4));
      mx = fmaxf(mx, __shfl_xor(mx, 8));
      float e0 = __expf(x0 - mx), e1 = __expf(x1 - mx),
            e2 = __expf(x2 - mx), e3 = __expf(x3 - mx);
      float sm = e0 + e1 + e2 + e3;
      sm += __shfl_xor(sm, 1); sm += __shfl_xor(sm, 2);
      sm += __shfl_xor(sm, 4); sm += __shfl_xor(sm, 8);
      float inv = 1.0f / sm;
      e0 *= inv; e1 *= inv; e2 *= inv; e3 *= inv;
      int s = (row0 + mi * 16 + hi * 4 + i) & 511;
      size_t hb = ((size_t)(b_idx * 16 + n_idx) * 512 + s) * 64;
      h_s[hb + 0  + lr] = f2bf(e0);
      h_s[hb + 16 + lr] = f2bf(e1);
      h_s[hb + 32 + lr] = f2bf(e2);
      h_s[hb + 48 + lr] = f2bf(e3);
      vpart[0] += e0; vpart[1] += e1; vpart[2] += e2; vpart[3] += e3;
    }
  }
#pragma unroll
  for (int ni = 0; ni < 4; ni++) {
    float t = vpart[ni];
    t += __shfl_xor(t, 16);
    t += __shfl_xor(t, 32);
    if (hi == 0) atomicAdd(&v[(b_idx * 16 + n_idx) * 64 + ni * 16 + lr], t);
  }
}

// ---------------- K2: h_t[bn][e][s] = h_s[bn][s][e] (LDS transpose, XOR swizzle) ----------------
__global__ __launch_bounds__(256)
void k_transpose(const u16* __restrict__ h_s, u16* __restrict__ h_t) {
  int bn = blockIdx.x;
  const u16* src = h_s + (size_t)bn * 32768;
  u16* dst = h_t + (size_t)bn * 32768;
  __shared__ u16 lds[64 * 512];
  int t = threadIdx.x;
  for (int k = 0; k < 64; k++) {
    int p = t + 256 * k;
    int s = p >> 5, e0 = (p & 31) * 2;
    unsigned u = reinterpret_cast<const unsigned*>(src)[p];
    lds[e0 * 512 + (s ^ e0)] = (u16)(u & 0xffffu);
    lds[(e0 + 1) * 512 + (s ^ (e0 + 1))] = (u16)(u >> 16);
  }
  __syncthreads();
  int e = t >> 2, s0 = (t & 3) * 128;
  for (int sb = 0; sb < 128; sb += 8) {
    unsigned pk[4];
#pragma unroll
    for (int jj = 0; jj < 4; jj++) {
      u16 lo = lds[e * 512 + ((s0 + sb + jj * 2) ^ e)];
      u16 hc = lds[e * 512 + ((s0 + sb + jj * 2 + 1) ^ e)];
      pk[jj] = (unsigned)lo | ((unsigned)hc << 16);
    }
    uint4 ov; ov.x = pk[0]; ov.y = pk[1]; ov.z = pk[2]; ov.w = pk[3];
    *reinterpret_cast<uint4*>(dst + e * 512 + s0 + sb) = ov;
  }
}

// ---------------- K3: z[b,n,o,e] = sum_h attn_w[o,n,e,h] * v[b,n,h] ----------------
// 2048 blocks (16 n x 128 o-tiles of 4): one (o,e) row per thread, 8 batches per thread.
// 32 waves/CU occupancy; vl[] reads are lane-uniform broadcasts.
__global__ __launch_bounds__(256)
void k_z(const float* __restrict__ attn_w, const float* __restrict__ v,
         u16* __restrict__ z) {
  int n = blockIdx.x >> 7, ot = blockIdx.x & 127;
  __shared__ float vl[512];
  int t = threadIdx.x;
  vl[t]       = v[((t >> 6) * 16 + n) * 64 + (t & 63)];
  vl[t + 256] = v[(((t + 256) >> 6) * 16 + n) * 64 + (t & 63)];
  __syncthreads();
  int ol = t >> 6, e = t & 63;
  int o = ot * 4 + ol;
  const float4* wp = reinterpret_cast<const float4*>(attn_w + ((size_t)(o * 16 + n) * 64 + e) * 64);
  float acc[8] = {};
#pragma unroll
  for (int j = 0; j < 16; j++) {
    float4 wv = wp[j];
#pragma unroll
    for (int bb = 0; bb < 8; bb++) {
      acc[bb] += wv.x * vl[bb * 64 + j * 4]
               + wv.y * vl[bb * 64 + j * 4 + 1]
               + wv.z * vl[bb * 64 + j * 4 + 2]
               + wv.w * vl[bb * 64 + j * 4 + 3];
    }
  }
#pragma unroll
  for (int bb = 0; bb < 8; bb++)
    z[((size_t)(bb * 16 + n) * 512 + o) * 64 + e] = f2bf(acc[bb]);
}

// ---------------- K4: scores -> softmax -> attn1 (f32 out) -> out_small ----------------
// Block: (b,n, 32-row s-tile). 8 waves. Pass1: each wave = 32 rows x 64-o strip (K=64).
// Softmax over 512 o via cross-wave LDS reduce. attn1 kept bf16 in swizzled LDS.
// Pass2: out_small(32x64) = attn1(32x512) @ h(512x64), wave = 16x16 tile, K=512.
__global__ __launch_bounds__(512)
void k_attn(const u16* __restrict__ h_s, const u16* __restrict__ h_t,
            const u16* __restrict__ z, float* __restrict__ attn1,
            u16* __restrict__ outs) {
  int bid = blockIdx.x;
  int bn = bid >> 4;
  int s0 = (bid & 15) * 32;
  int b = bn >> 4, n = bn & 15;
  int tid = threadIdx.x;
  int w = tid >> 6, lane = tid & 63, lr = lane & 15, hi = lane >> 4;

  __shared__ u16 pa[32 * 512];     // attn1 bf16, 8-elem-granule XOR swizzle
  __shared__ float red[8 * 32];
  __shared__ float gred[32];

  const u16* hsb = h_s + (size_t)bn * 32768;
  const u16* htb = h_t + (size_t)bn * 32768;
  const u16* zb  = z   + (size_t)bn * 32768;

  f32x4 acc[2][4] = {};
  {
    bfrag a[2][2], bb[4][2];
#pragma unroll
    for (int kk = 0; kk < 2; kk++) {
      int ko = kk * 32 + hi * 8;
#pragma unroll
      for (int mi = 0; mi < 2; mi++)
        a[mi][kk] = *reinterpret_cast<const bfrag*>(hsb + (s0 + mi * 16 + lr) * 64 + ko);
#pragma unroll
      for (int ni = 0; ni < 4; ni++)
        bb[ni][kk] = *reinterpret_cast<const bfrag*>(zb + (w * 64 + ni * 16 + lr) * 64 + ko);
    }
#pragma unroll
    for (int kk = 0; kk < 2; kk++)
#pragma unroll
      for (int mi = 0; mi < 2; mi++)
#pragma unroll
        for (int ni = 0; ni < 4; ni++)
          acc[mi][ni] = MFMA16(a[mi][kk], bb[ni][kk], acc[mi][ni]);
  }
  const float scale = 6.9053396600248786e-04f;  // 1/(64*sqrt(512))
#pragma unroll
  for (int mi = 0; mi < 2; mi++)
#pragma unroll
    for (int ni = 0; ni < 4; ni++)
#pragma unroll
      for (int i = 0; i < 4; i++) acc[mi][ni][i] *= scale;

  // per-row max (strip) -> LDS
#pragma unroll
  for (int mi = 0; mi < 2; mi++)
#pragma unroll
    for (int i = 0; i < 4; i++) {
      float mx = fmaxf(fmaxf(acc[mi][0][i], acc[mi][1][i]),
                       fmaxf(acc[mi][2][i], acc[mi][3][i]));
      mx = fmaxf(mx, __shfl_xor(mx, 1));
      mx = fmaxf(mx, __shfl_xor(mx, 2));
      mx = fmaxf(mx, __shfl_xor(mx, 4));
      mx = fmaxf(mx, __shfl_xor(mx, 8));
      if (lr == 0) red[w * 32 + mi * 16 + hi * 4 + i] = mx;
    }
  __syncthreads();
  if (tid < 32) {
    float g = red[tid];
#pragma unroll
    for (int w2 = 1; w2 < 8; w2++) g = fmaxf(g, red[w2 * 32 + tid]);
    gred[tid] = g;
  }
  __syncthreads();
  float p[2][4][4];
#pragma unroll
  for (int mi = 0; mi < 2; mi++)
#pragma unroll
    for (int i = 0; i < 4; i++) {
      float gm = gred[mi * 16 + hi * 4 + i];
      float sm = 0.f;
#pragma unroll
      for (int ni = 0; ni < 4; ni++) {
        p[mi][ni][i] = __expf(acc[mi][ni][i] - gm);
        sm += p[mi][ni][i];
      }
      sm += __shfl_xor(sm, 1); sm += __shfl_xor(sm, 2);
      sm += __shfl_xor(sm, 4); sm += __shfl_xor(sm, 8);
      if (lr == 0) red[w * 32 + mi * 16 + hi * 4 + i] = sm;
    }
  __syncthreads();
  if (tid < 32) {
    float g = 0.f;
#pragma unroll
    for (int w2 = 0; w2 < 8; w2++) g += red[w2 * 32 + tid];
    gred[tid] = 1.0f / g;
  }
  __syncthreads();
  float* a1b = attn1 + ((size_t)bn * 512 + s0) * 512;
#pragma unroll
  for (int mi = 0; mi < 2; mi++)
#pragma unroll
    for (int i = 0; i < 4; i++) {
      int r = mi * 16 + hi * 4 + i;
      float gi = gred[r];
#pragma unroll
      for (int ni = 0; ni < 4; ni++) {
        float val = p[mi][ni][i] * gi;
        int c = w * 64 + ni * 16 + lr;
        a1b[(size_t)r * 512 + c] = val;
        int g = c >> 3, j = c & 7;
        pa[r * 512 + ((g ^ (r & 7)) * 8 + j)] = f2bf(val);
      }
    }
  __syncthreads();
  // pass2: out_small = attn1 @ h  (B from h_t, contiguous k)
  int sm2 = (w >> 2) * 16, e0 = (w & 3) * 16;
  f32x4 oacc = {};
#pragma unroll 4
  for (int ks = 0; ks < 16; ks++) {
    int row = sm2 + lr;
    int g = ks * 4 + hi;
    bfrag av = *reinterpret_cast<const bfrag*>(pa + row * 512 + ((g ^ (row & 7)) * 8));
    bfrag bv = *reinterpret_cast<const bfrag*>(htb + (e0 + lr) * 512 + ks * 32 + hi * 8);
    oacc = MFMA16(av, bv, oacc);
  }
#pragma unroll
  for (int i = 0; i < 4; i++) {
    int s = s0 + sm2 + hi * 4 + i;
    outs[((size_t)b * 512 + s) * 1024 + n * 64 + e0 + lr] = f2bf(oacc[i]);
  }
}

// ---------------- K5: out = out_small @ W_out^T + b_out ----------------
__global__ __launch_bounds__(256)
void k_gemm2(const u16* __restrict__ ab, const u16* __restrict__ wb,
             const float* __restrict__ bias, float* __restrict__ out) {
  int bx = blockIdx.x & 15;
  int by = blockIdx.x >> 4;
  int tid = threadIdx.x;
  int w = tid >> 6, lane = tid & 63, lr = lane & 15, hi = lane >> 4;
  int row0 = by * 128 + w * 32;
  int col0 = bx * 64;
  f32x4 acc[2][4] = {};
  const u16* Ab = ab + (size_t)row0 * 1024;
  const u16* Bb = wb + (size_t)col0 * 1024;
  for (int k0 = 0; k0 < 1024; k0 += 32) {
    int ko = k0 + hi * 8;
    bfrag a[2], b[4];
#pragma unroll
    for (int mi = 0; mi < 2; mi++)
      a[mi] = *reinterpret_cast<const bfrag*>(Ab + (mi * 16 + lr) * 1024 + ko);
#pragma unroll
    for (int ni = 0; ni < 4; ni++)
      b[ni] = *reinterpret_cast<const bfrag*>(Bb + (ni * 16 + lr) * 1024 + ko);
#pragma unroll
    for (int mi = 0; mi < 2; mi++)
#pragma unroll
      for (int ni = 0; ni < 4; ni++)
        acc[mi][ni] = MFMA16(a[mi], b[ni], acc[mi][ni]);
  }
  float bia[4];
#pragma unroll
  for (int ni = 0; ni < 4; ni++) bia[ni] = bias[col0 + ni * 16 + lr];
#pragma unroll
  for (int mi = 0; mi < 2; mi++)
#pragma unroll
    for (int i = 0; i < 4; i++) {
      int r = row0 + mi * 16 + hi * 4 + i;
#pragma unroll
      for (int ni = 0; ni < 4; ni++)
        out[(size_t)r * 1024 + col0 + ni * 16 + lr] = acc[mi][ni][i] + bia[ni];
    }
}

extern "C" void kernel_launch(void* const* d_in, const int* in_sizes, int n_in,
                              void* d_out, int out_size, void* d_ws, size_t ws_size,
                              hipStream_t stream) {
  const float* x      = (const float*)d_in[0];
  const float* W_in   = (const float*)d_in[1];
  const float* b_in   = (const float*)d_in[2];
  const float* attn_w = (const float*)d_in[3];
  const float* W_out  = (const float*)d_in[4];
  const float* b_out  = (const float*)d_in[5];
  float* out   = (float*)d_out;                 // [8,512,1024] f32
  float* attn1 = out + 4194304;                 // [8,16,512,512] f32

  char* w = (char*)d_ws;
  u16*   xb    = (u16*)(w + 0);                 //  8 MB  [4096][1024]  (dead after k_gemm1)
  u16*   wbin  = (u16*)(w + 8388608);           //  2 MB  [1024][1024]
  u16*   wbout = (u16*)(w + 10485760);          //  2 MB
  u16*   h_s   = (u16*)(w + 12582912);          //  8 MB  [bn][512][64]
  u16*   h_t   = (u16*)(w + 20971520);          //  8 MB  [bn][64][512]
  u16*   zbuf  = (u16*)(w + 29360128);          //  8 MB  [bn][512][64]
  float* vbuf  = (float*)(w + 37748736);        // 32 KB  [bn][64]
  u16*   outs  = xb;                            //  reuses xb slot (k_attn writes after k_gemm1 done)
  // total ws footprint: 37,781,504 + 32,768 = 37,814,272 bytes

  hipMemsetAsync(vbuf, 0, 8192 * sizeof(float), stream);
  k_cast<<<4096, 256, 0, stream>>>(x, xb, 1048576);
  k_cast<<<1024, 256, 0, stream>>>(W_in, wbin, 262144);
  k_cast<<<1024, 256, 0, stream>>>(W_out, wbout, 262144);
  k_gemm1<<<512, 256, 0, stream>>>(xb, wbin, b_in, h_s, vbuf);
  k_transpose<<<128, 256, 0, stream>>>(h_s, h_t);
  k_z<<<2048, 256, 0, stream>>>(attn_w, vbuf, zbuf);
  k_attn<<<2048, 512, 0, stream>>>(h_s, h_t, zbuf, attn1, outs);
  k_gemm2<<<512, 256, 0, stream>>>(outs, wbout, b_out, out);
}